// Round 1
// baseline (269.754 us; speedup 1.0000x reference)
//
#include <hip/hip_runtime.h>
#include <hip/hip_bf16.h>
#include <stdint.h>

// Problem constants: B=4, S=8192, E=1024, heads=16, e=64
static constexpr int MTOT = 32768;   // B*S
static constexpr int KD   = 1024;    // E (contraction dim for both GEMMs)
static constexpr int ND   = 1024;    // output cols for both GEMMs

typedef __bf16 bf16x8 __attribute__((ext_vector_type(8)));
typedef float  f32x4  __attribute__((ext_vector_type(4)));

__device__ __forceinline__ unsigned short f2bf_rne(float f) {
  union { float f; uint32_t u; } c; c.f = f;
  uint32_t u = c.u;
  uint32_t r = (u + 0x7fffu + ((u >> 16) & 1u)) >> 16;
  return (unsigned short)r;
}

__global__ void cast_f32_to_bf16(const float* __restrict__ src,
                                 unsigned short* __restrict__ dst, int n4) {
  int idx = blockIdx.x * blockDim.x + threadIdx.x;
  int stride = gridDim.x * blockDim.x;
  for (int i = idx; i < n4; i += stride) {
    float4 v = reinterpret_cast<const float4*>(src)[i];
    ushort4 o;
    o.x = f2bf_rne(v.x); o.y = f2bf_rne(v.y);
    o.z = f2bf_rne(v.z); o.w = f2bf_rne(v.w);
    reinterpret_cast<ushort4*>(dst)[i] = o;
  }
}

__device__ __forceinline__ void gload_lds16(const void* g, void* lds) {
  __builtin_amdgcn_global_load_lds(
      (const __attribute__((address_space(1))) unsigned int*)g,
      (__attribute__((address_space(3))) unsigned int*)lds, 16, 0, 0);
}

// C = A * B^T, A:[MTOT][KD] bf16 row-major, Bm:[ND][KD] bf16 row-major.
// 128x128 tile, BK=32, 4 waves (2x2), each wave 64x64 via 4x4 16x16x32 MFMA frags.
// SOFTMAX=1: epilogue does per-row softmax over the wave's 64 cols (one head
// block) with logits = acc/4, writes bf16. SOFTMAX=0: writes f32.
template <int SOFTMAX>
__global__ __launch_bounds__(256)
void gemm_bt(const unsigned short* __restrict__ A,
             const unsigned short* __restrict__ Bm,
             void* __restrict__ Cout) {
  __shared__ __align__(16) unsigned short Alds[128 * 32];
  __shared__ __align__(16) unsigned short Blds[128 * 32];

  const int tid  = threadIdx.x;
  const int lane = tid & 63;
  const int wid  = tid >> 6;
  const int bid  = blockIdx.x;
  const int brow = (bid >> 3) * 128;   // ND/128 == 8 col tiles
  const int bcol = (bid & 7) * 128;
  const int wr = wid >> 1, wc = wid & 1;
  const int fr = lane & 15;            // frag row/col within 16
  const int fq = lane >> 4;            // k-group 0..3

  // staging: wave wid covers segments {2*wid, 2*wid+1}; each segment = 16 rows
  // of the [128][32] bf16 tile (1 KiB). lane -> row (lane>>2), k (lane&3)*8.
  const int seg0  = wid * 2;
  const int srow  = lane >> 2;
  const int skoff = (lane & 3) * 8;

  f32x4 acc[4][4] = {};

  const size_t a_base0 = (size_t)(brow + seg0 * 16 + srow) * KD + skoff;
  const size_t a_base1 = a_base0 + (size_t)16 * KD;
  const size_t b_base0 = (size_t)(bcol + seg0 * 16 + srow) * KD + skoff;
  const size_t b_base1 = b_base0 + (size_t)16 * KD;

  for (int kt = 0; kt < KD / 32; ++kt) {
    const int k0 = kt * 32;
    gload_lds16(A  + a_base0 + k0, &Alds[(seg0 + 0) * 512]);
    gload_lds16(A  + a_base1 + k0, &Alds[(seg0 + 1) * 512]);
    gload_lds16(Bm + b_base0 + k0, &Blds[(seg0 + 0) * 512]);
    gload_lds16(Bm + b_base1 + k0, &Blds[(seg0 + 1) * 512]);
    __syncthreads();   // drains vmcnt -> LDS tiles ready

    bf16x8 afr[4], bfr[4];
    #pragma unroll
    for (int m = 0; m < 4; ++m)
      afr[m] = *reinterpret_cast<const bf16x8*>(
          &Alds[(wr * 64 + m * 16 + fr) * 32 + fq * 8]);
    #pragma unroll
    for (int n = 0; n < 4; ++n)
      bfr[n] = *reinterpret_cast<const bf16x8*>(
          &Blds[(wc * 64 + n * 16 + fr) * 32 + fq * 8]);

    #pragma unroll
    for (int m = 0; m < 4; ++m)
      #pragma unroll
      for (int n = 0; n < 4; ++n)
        acc[m][n] = __builtin_amdgcn_mfma_f32_16x16x32_bf16(
            afr[m], bfr[n], acc[m][n], 0, 0, 0);
    __syncthreads();   // protect LDS before next stage
  }

  if constexpr (SOFTMAX) {
    // logits = acc * 0.25; softmax over the wave's 64 cols (= one head block).
    // Row r's 64 values live in n=0..3 frags across the 16 lanes sharing fq.
    unsigned short* attn = reinterpret_cast<unsigned short*>(Cout);
    constexpr float CEXP = 0.25f * 1.44269504088896340736f; // log2(e)/4
    #pragma unroll
    for (int m = 0; m < 4; ++m) {
      const int row = brow + wr * 64 + m * 16 + fq * 4;
      #pragma unroll
      for (int j = 0; j < 4; ++j) {
        float v0 = acc[m][0][j], v1 = acc[m][1][j];
        float v2 = acc[m][2][j], v3 = acc[m][3][j];
        float mx = fmaxf(fmaxf(v0, v1), fmaxf(v2, v3));
        #pragma unroll
        for (int s = 1; s < 16; s <<= 1) mx = fmaxf(mx, __shfl_xor(mx, s, 64));
        float p0 = exp2f((v0 - mx) * CEXP);
        float p1 = exp2f((v1 - mx) * CEXP);
        float p2 = exp2f((v2 - mx) * CEXP);
        float p3 = exp2f((v3 - mx) * CEXP);
        float sm = p0 + p1 + p2 + p3;
        #pragma unroll
        for (int s = 1; s < 16; s <<= 1) sm += __shfl_xor(sm, s, 64);
        const float inv = 1.0f / sm;
        unsigned short* dst =
            attn + (size_t)(row + j) * ND + (bcol + wc * 64 + fr);
        dst[0]  = f2bf_rne(p0 * inv);
        dst[16] = f2bf_rne(p1 * inv);
        dst[32] = f2bf_rne(p2 * inv);
        dst[48] = f2bf_rne(p3 * inv);
      }
    }
  } else {
    float* Cf = reinterpret_cast<float*>(Cout);
    #pragma unroll
    for (int m = 0; m < 4; ++m) {
      const int row = brow + wr * 64 + m * 16 + fq * 4;
      #pragma unroll
      for (int n = 0; n < 4; ++n) {
        const int col = bcol + wc * 64 + n * 16 + fr;
        #pragma unroll
        for (int j = 0; j < 4; ++j)
          Cf[(size_t)(row + j) * ND + col] = acc[m][n][j];
      }
    }
  }
}

extern "C" void kernel_launch(void* const* d_in, const int* in_sizes, int n_in,
                              void* d_out, int out_size, void* d_ws, size_t ws_size,
                              hipStream_t stream) {
  const float* x  = (const float*)d_in[0];   // [4,8192,1024] f32
  const float* W1 = (const float*)d_in[1];   // [3072,1024]  f32 (only rows 0..1023 = Wq matter)
  const float* W2 = (const float*)d_in[2];   // [1024,1024]  f32
  float* out = (float*)d_out;                // [4,8192,1024] f32

  // ws layout (total 132 MiB):
  //   xb   bf16[32768*1024]  @ 0        (64 MiB)
  //   w1b  bf16[1024*1024]   @ 64 MiB   ( 2 MiB)
  //   w2b  bf16[1024*1024]   @ 66 MiB   ( 2 MiB)
  //   attn bf16[32768*1024]  @ 68 MiB   (64 MiB)
  char* ws = (char*)d_ws;
  unsigned short* xb   = (unsigned short*)(ws);
  unsigned short* w1b  = (unsigned short*)(ws + (size_t)67108864);
  unsigned short* w2b  = (unsigned short*)(ws + (size_t)69206016);
  unsigned short* attn = (unsigned short*)(ws + (size_t)71303168);

  cast_f32_to_bf16<<<2048, 256, 0, stream>>>(x,  xb,  MTOT * KD / 4);
  cast_f32_to_bf16<<<512,  256, 0, stream>>>(W1, w1b, KD * KD / 4); // q rows only
  cast_f32_to_bf16<<<512,  256, 0, stream>>>(W2, w2b, KD * KD / 4);

  // GEMM1 + fused head-block softmax -> bf16 attn
  gemm_bt<1><<<dim3((MTOT / 128) * (ND / 128)), dim3(256), 0, stream>>>(
      xb, w1b, (void*)attn);
  // GEMM2 -> f32 out
  gemm_bt<0><<<dim3((MTOT / 128) * (ND / 128)), dim3(256), 0, stream>>>(
      attn, w2b, (void*)out);
}

// Round 2
// 205.823 us; speedup vs baseline: 1.3106x; 1.3106x over previous
//
#include <hip/hip_runtime.h>
#include <hip/hip_bf16.h>
#include <stdint.h>

// B=4, S=8192, E=1024, heads=16 -> math collapses to:
//   Q = x @ W1[0:1024].T ; A = per-64-col-block softmax(Q/4) ; out = A @ W2.T
static constexpr int MTOT = 32768;
static constexpr int KD   = 1024;
static constexpr int ND   = 1024;

static constexpr int BM = 256, BN = 256, BK = 64;
static constexpr int NT = KD / BK;              // 16 K-tiles
static constexpr int BUF_BYTES = 65536;         // per-buffer: A 32K + B 32K
static constexpr int BOFF = 32768;              // B offset within buffer
static constexpr int HALF = 16384;              // one staging unit (128 rows x 64 cols bf16)

typedef __bf16 bf16x8 __attribute__((ext_vector_type(8)));
typedef float  f32x4  __attribute__((ext_vector_type(4)));

__device__ __forceinline__ unsigned short f2bf_rne(float f) {
  union { float f; uint32_t u; } c; c.f = f;
  uint32_t u = c.u;
  return (unsigned short)((u + 0x7fffu + ((u >> 16) & 1u)) >> 16);
}

__global__ void cast_f32_to_bf16(const float* __restrict__ src,
                                 unsigned short* __restrict__ dst, int n4) {
  int idx = blockIdx.x * blockDim.x + threadIdx.x;
  int stride = gridDim.x * blockDim.x;
  for (int i = idx; i < n4; i += stride) {
    float4 v = reinterpret_cast<const float4*>(src)[i];
    ushort4 o;
    o.x = f2bf_rne(v.x); o.y = f2bf_rne(v.y);
    o.z = f2bf_rne(v.z); o.w = f2bf_rne(v.w);
    reinterpret_cast<ushort4*>(dst)[i] = o;
  }
}

__device__ __forceinline__ void gload_lds16(const void* g, void* lds) {
  __builtin_amdgcn_global_load_lds(
      (const __attribute__((address_space(1))) unsigned int*)g,
      (__attribute__((address_space(3))) unsigned int*)lds, 16, 0, 0);
}

// 256x256 tile, BK=64, 8 waves (2Mx4N), double-buffered 128 KiB LDS,
// 8-phase-per-2-K-tiles schedule with counted vmcnt (T2+T3+T4+T5).
template <int SOFTMAX>
__global__ __launch_bounds__(512, 2)
void gemm8(const unsigned short* __restrict__ A,
           const unsigned short* __restrict__ Bm,
           void* __restrict__ Cout) {
  extern __shared__ __align__(16) char ldsc[];

  const int tid  = threadIdx.x;
  const int lane = tid & 63;
  const int wid  = tid >> 6;
  const int wm = wid >> 2, wn = wid & 3;       // wave tile: 128 rows x 64 cols
  const int fr = lane & 15, fq = lane >> 4;
  const int bid  = blockIdx.x;
  const int brow = (bid >> 2) * BM;            // 128 row tiles
  const int bcol = (bid & 3) * BN;             // 4 col tiles

  // --- staging precompute (linear LDS dest + inverse-swizzled global src) ---
  // unit = 128 rows x 64 bf16 cols (16 KiB). thread tid, load j in {0,1}:
  //   LDS linear byte O=(j*512+tid)*16 -> row=j*64+(tid>>3), slot=tid&7.
  //   read-side swizzle: slot' = slot ^ (row&7)  (row&7 == (tid>>3)&7 for both j)
  const int srow  = tid >> 3;                              // 0..63
  const int sslot = (tid & 7) ^ (srow & 7);
  const unsigned short* gA = A  + (size_t)(brow + srow) * KD + sslot * 8;
  const unsigned short* gB = Bm + (size_t)(bcol + srow) * KD + sslot * 8;
  const int wofs = wid << 10;                              // wave's 1KiB slice

  f32x4  acc[8][4] = {};
  bf16x8 a0[4][2], a1[4][2], bb[2][2];

  auto STAGE = [&](const unsigned short* g, int h, int kt, int b, int opOff) {
    const unsigned short* gu = g + (size_t)(h * 128) * KD + kt * BK;
    char* du = ldsc + b * BUF_BYTES + opOff + h * HALF + wofs;
    gload_lds16(gu, du);
    gload_lds16(gu + (size_t)64 * KD, du + 8192);
  };

  auto rdA = [&](int b, bf16x8 (*dst)[2], int mBase) {
    const char* base = ldsc + b * BUF_BYTES + wm * HALF;
    #pragma unroll
    for (int mm = 0; mm < 4; ++mm) {
      const int r = (mBase + mm) * 16 + fr;
      #pragma unroll
      for (int ks = 0; ks < 2; ++ks)
        dst[mm][ks] = *(const bf16x8*)(base + (r << 7) +
                        ((ks * 64 + fq * 16) ^ ((r & 7) << 4)));
    }
  };
  auto rdB = [&](int b, int nBase) {
    const char* base = ldsc + b * BUF_BYTES + BOFF + (wn >> 1) * HALF;
    #pragma unroll
    for (int nn = 0; nn < 2; ++nn) {
      const int r = (wn & 1) * 64 + (nBase + nn) * 16 + fr;
      #pragma unroll
      for (int ks = 0; ks < 2; ++ks)
        bb[nn][ks] = *(const bf16x8*)(base + (r << 7) +
                       ((ks * 64 + fq * 16) ^ ((r & 7) << 4)));
    }
  };
  auto MFMA16 = [&](int mBase, int nBase, bf16x8 (*af)[2]) {
    #pragma unroll
    for (int mm = 0; mm < 4; ++mm)
      #pragma unroll
      for (int nn = 0; nn < 2; ++nn)
        #pragma unroll
        for (int ks = 0; ks < 2; ++ks)
          acc[mBase + mm][nBase + nn] = __builtin_amdgcn_mfma_f32_16x16x32_bf16(
              af[mm][ks], bb[nn][ks], acc[mBase + mm][nBase + nn], 0, 0, 0);
  };

  // --- prologue: tile0 (4 units) + A halves of tile1 ---
  STAGE(gA, 0, 0, 0, 0);    STAGE(gA, 1, 0, 0, 0);
  STAGE(gB, 0, 0, 0, BOFF); STAGE(gB, 1, 0, 0, BOFF);
  STAGE(gA, 0, 1, 1, 0);    STAGE(gA, 1, 1, 1, 0);
  asm volatile("s_waitcnt vmcnt(4)" ::: "memory");   // tile0 landed; A(1) in flight
  __builtin_amdgcn_s_barrier();

  for (int T = 0; T < NT; ++T) {
    const int cur = T & 1, nxt = cur ^ 1;
    const int tp1 = (T + 1 < NT) ? T + 1 : NT - 1;
    const int tp2 = (T + 2 < NT) ? T + 2 : NT - 1;

    // P1: quadrant (m0-3, n0-1)
    rdA(cur, a0, 0); rdB(cur, 0);
    STAGE(gB, 0, tp1, nxt, BOFF);        // other buffer: tile T-1 B fully read
    __builtin_amdgcn_s_barrier();
    asm volatile("s_waitcnt lgkmcnt(0)" ::: "memory");
    __builtin_amdgcn_s_setprio(1);
    MFMA16(0, 0, a0);
    __builtin_amdgcn_s_setprio(0);
    __builtin_amdgcn_s_barrier();

    // P2: quadrant (m4-7, n0-1)
    rdA(cur, a1, 4);
    STAGE(gB, 1, tp1, nxt, BOFF);
    __builtin_amdgcn_s_barrier();
    asm volatile("s_waitcnt lgkmcnt(0)" ::: "memory");
    __builtin_amdgcn_s_setprio(1);
    MFMA16(4, 0, a1);
    __builtin_amdgcn_s_setprio(0);
    __builtin_amdgcn_s_barrier();

    // P3: quadrant (m4-7, n2-3)
    rdB(cur, 2);
    STAGE(gA, 0, tp2, cur, 0);           // cur A-half0: its reads done end-P2
    __builtin_amdgcn_s_barrier();
    asm volatile("s_waitcnt lgkmcnt(0)" ::: "memory");
    __builtin_amdgcn_s_setprio(1);
    MFMA16(4, 2, a1);
    __builtin_amdgcn_s_setprio(0);
    __builtin_amdgcn_s_barrier();

    // P4: quadrant (m0-3, n2-3); per-K-tile counted vmcnt (never 0)
    STAGE(gA, 1, tp2, cur, 0);
    asm volatile("s_waitcnt vmcnt(4)" ::: "memory"); // tile T+1 fully landed
    __builtin_amdgcn_s_barrier();
    __builtin_amdgcn_s_setprio(1);
    MFMA16(0, 2, a0);
    __builtin_amdgcn_s_setprio(0);
    __builtin_amdgcn_s_barrier();
  }

  if constexpr (SOFTMAX) {
    // logits = acc/4; softmax over the wave's 64-col block (= one head block)
    unsigned short* attn = reinterpret_cast<unsigned short*>(Cout);
    constexpr float CEXP = 0.25f * 1.44269504088896340736f; // log2(e)/4
    #pragma unroll
    for (int m = 0; m < 8; ++m) {
      const int row = brow + wm * 128 + m * 16 + fq * 4;
      #pragma unroll
      for (int j = 0; j < 4; ++j) {
        float v0 = acc[m][0][j], v1 = acc[m][1][j];
        float v2 = acc[m][2][j], v3 = acc[m][3][j];
        float mx = fmaxf(fmaxf(v0, v1), fmaxf(v2, v3));
        #pragma unroll
        for (int s = 1; s < 16; s <<= 1) mx = fmaxf(mx, __shfl_xor(mx, s, 64));
        float p0 = exp2f((v0 - mx) * CEXP);
        float p1 = exp2f((v1 - mx) * CEXP);
        float p2 = exp2f((v2 - mx) * CEXP);
        float p3 = exp2f((v3 - mx) * CEXP);
        float sm = p0 + p1 + p2 + p3;
        #pragma unroll
        for (int s = 1; s < 16; s <<= 1) sm += __shfl_xor(sm, s, 64);
        const float inv = 1.0f / sm;
        unsigned short* dst =
            attn + (size_t)(row + j) * ND + (bcol + wn * 64 + fr);
        dst[0]  = f2bf_rne(p0 * inv);
        dst[16] = f2bf_rne(p1 * inv);
        dst[32] = f2bf_rne(p2 * inv);
        dst[48] = f2bf_rne(p3 * inv);
      }
    }
  } else {
    float* Cf = reinterpret_cast<float*>(Cout);
    #pragma unroll
    for (int m = 0; m < 8; ++m) {
      const int row = brow + wm * 128 + m * 16 + fq * 4;
      #pragma unroll
      for (int n = 0; n < 4; ++n) {
        const int col = bcol + wn * 64 + n * 16 + fr;
        #pragma unroll
        for (int j = 0; j < 4; ++j)
          Cf[(size_t)(row + j) * ND + col] = acc[m][n][j];
      }
    }
  }
}

extern "C" void kernel_launch(void* const* d_in, const int* in_sizes, int n_in,
                              void* d_out, int out_size, void* d_ws, size_t ws_size,
                              hipStream_t stream) {
  const float* x  = (const float*)d_in[0];   // [4,8192,1024] f32
  const float* W1 = (const float*)d_in[1];   // [3072,1024]  f32 (rows 0..1023 = Wq)
  const float* W2 = (const float*)d_in[2];   // [1024,1024]  f32
  float* out = (float*)d_out;

  char* ws = (char*)d_ws;
  unsigned short* xb   = (unsigned short*)(ws);
  unsigned short* w1b  = (unsigned short*)(ws + (size_t)67108864);
  unsigned short* w2b  = (unsigned short*)(ws + (size_t)69206016);
  unsigned short* attn = (unsigned short*)(ws + (size_t)71303168);

  // opt-in to 128 KiB dynamic LDS (idempotent, host-side, graph-safe)
  hipFuncSetAttribute(reinterpret_cast<const void*>(gemm8<1>),
                      hipFuncAttributeMaxDynamicSharedMemorySize, 131072);
  hipFuncSetAttribute(reinterpret_cast<const void*>(gemm8<0>),
                      hipFuncAttributeMaxDynamicSharedMemorySize, 131072);

  cast_f32_to_bf16<<<2048, 256, 0, stream>>>(x,  xb,  MTOT * KD / 4);
  cast_f32_to_bf16<<<512,  256, 0, stream>>>(W1, w1b, KD * KD / 4);
  cast_f32_to_bf16<<<512,  256, 0, stream>>>(W2, w2b, KD * KD / 4);

  const int nblk = (MTOT / BM) * (ND / BN);   // 128 * 4 = 512
  gemm8<1><<<nblk, 512, 131072, stream>>>(xb, w1b, (void*)attn);
  gemm8<0><<<nblk, 512, 131072, stream>>>(attn, w2b, (void*)out);
}

// Round 3
// 197.473 us; speedup vs baseline: 1.3660x; 1.0423x over previous
//
#include <hip/hip_runtime.h>
#include <hip/hip_bf16.h>
#include <stdint.h>

// B=4, S=8192, E=1024, heads=16 -> math collapses to:
//   Q = x @ W1[0:1024].T ; A = per-64-col-block softmax(Q/4) ; out = A @ W2.T
static constexpr int MTOT = 32768;
static constexpr int KD   = 1024;
static constexpr int ND   = 1024;

static constexpr int BM = 256, BN = 256, BK = 64;
static constexpr int NT = KD / BK;              // 16 K-tiles
static constexpr int BUF_BYTES = 65536;         // per-buffer: A 32K + B 32K
static constexpr int BOFF = 32768;              // B offset within buffer
static constexpr int HALF = 16384;              // one staging unit (128 rows x 64 cols bf16)

typedef __bf16 bf16x8 __attribute__((ext_vector_type(8)));
typedef float  f32x4  __attribute__((ext_vector_type(4)));

__device__ __forceinline__ unsigned short f2bf_rne(float f) {
  union { float f; uint32_t u; } c; c.f = f;
  uint32_t u = c.u;
  return (unsigned short)((u + 0x7fffu + ((u >> 16) & 1u)) >> 16);
}

__global__ void cast_f32_to_bf16(const float* __restrict__ src,
                                 unsigned short* __restrict__ dst, int n4) {
  int idx = blockIdx.x * blockDim.x + threadIdx.x;
  int stride = gridDim.x * blockDim.x;
  for (int i = idx; i < n4; i += stride) {
    float4 v = reinterpret_cast<const float4*>(src)[i];
    ushort4 o;
    o.x = f2bf_rne(v.x); o.y = f2bf_rne(v.y);
    o.z = f2bf_rne(v.z); o.w = f2bf_rne(v.w);
    reinterpret_cast<ushort4*>(dst)[i] = o;
  }
}

__device__ __forceinline__ void gload_lds16(const void* g, void* lds) {
  __builtin_amdgcn_global_load_lds(
      (const __attribute__((address_space(1))) unsigned int*)g,
      (__attribute__((address_space(3))) unsigned int*)lds, 16, 0, 0);
}

// 256x256 tile, BK=64, 8 waves (2Mx4N), double-buffered 128 KiB LDS,
// 4-phase-per-K-tile schedule, counted vmcnt, reg-double-buffered B frags,
// XCD-aware block swizzle (T1+T2+T3+T4+T5).
template <int SOFTMAX>
__global__ __launch_bounds__(512, 2)
void gemm8(const unsigned short* __restrict__ A,
           const unsigned short* __restrict__ Bm,
           void* __restrict__ Cout) {
  extern __shared__ __align__(16) char ldsc[];

  const int tid  = threadIdx.x;
  const int lane = tid & 63;
  const int wid  = tid >> 6;
  const int wm = wid >> 2, wn = wid & 3;       // wave tile: 128 rows x 64 cols
  const int fr = lane & 15, fq = lane >> 4;

  // T1: bijective XCD swizzle. 512 blocks, 8 XCDs, 64 blocks/XCD chunk.
  // Consecutive logical ids (same brow, 4 bcols) land on ONE XCD -> A-panel
  // fetched once into that XCD's L2.
  const int bid0 = blockIdx.x;
  const int bid  = ((bid0 & 7) << 6) | (bid0 >> 3);
  const int brow = (bid >> 2) * BM;            // 128 row tiles
  const int bcol = (bid & 3) * BN;             // 4 col tiles

  // staging: linear LDS dest + inverse-swizzled global src (rule #21).
  const int srow  = tid >> 3;                              // 0..63
  const int sslot = (tid & 7) ^ (srow & 7);
  const unsigned short* gA = A  + (size_t)(brow + srow) * KD + sslot * 8;
  const unsigned short* gB = Bm + (size_t)(bcol + srow) * KD + sslot * 8;
  const int wofs = tid * 16;                               // NOTE: == linear dest

  f32x4  acc[8][4] = {};
  bf16x8 a0[4][2], a1[4][2], bA[2][2], bB[2][2];

  auto STAGE = [&](const unsigned short* g, int h, int kt, int b, int opOff) {
    const unsigned short* gu = g + (size_t)(h * 128) * KD + kt * BK;
    char* du = ldsc + b * BUF_BYTES + opOff + h * HALF + (wid << 10);
    gload_lds16(gu, du);
    gload_lds16(gu + (size_t)64 * KD, du + 8192);
  };

  auto rdA = [&](int b, bf16x8 (*dst)[2], int mBase) {
    const char* base = ldsc + b * BUF_BYTES + wm * HALF;
    #pragma unroll
    for (int mm = 0; mm < 4; ++mm) {
      const int r = (mBase + mm) * 16 + fr;
      #pragma unroll
      for (int ks = 0; ks < 2; ++ks)
        dst[mm][ks] = *(const bf16x8*)(base + (r << 7) +
                        ((ks * 64 + fq * 16) ^ ((r & 7) << 4)));
    }
  };
  auto rdB = [&](int b, int nBase, bf16x8 (*dst)[2]) {
    const char* base = ldsc + b * BUF_BYTES + BOFF + (wn >> 1) * HALF;
    #pragma unroll
    for (int nn = 0; nn < 2; ++nn) {
      const int r = (wn & 1) * 64 + (nBase + nn) * 16 + fr;
      #pragma unroll
      for (int ks = 0; ks < 2; ++ks)
        dst[nn][ks] = *(const bf16x8*)(base + (r << 7) +
                       ((ks * 64 + fq * 16) ^ ((r & 7) << 4)));
    }
  };
  auto MFMA16 = [&](int mBase, int nBase, bf16x8 (*af)[2], bf16x8 (*bf)[2]) {
    #pragma unroll
    for (int mm = 0; mm < 4; ++mm)
      #pragma unroll
      for (int nn = 0; nn < 2; ++nn)
        #pragma unroll
        for (int ks = 0; ks < 2; ++ks)
          acc[mBase + mm][nBase + nn] = __builtin_amdgcn_mfma_f32_16x16x32_bf16(
              af[mm][ks], bf[nn][ks], acc[mBase + mm][nBase + nn], 0, 0, 0);
  };

  // --- prologue: tile0 (4 units) + A halves of tile1 ---
  STAGE(gA, 0, 0, 0, 0);    STAGE(gA, 1, 0, 0, 0);
  STAGE(gB, 0, 0, 0, BOFF); STAGE(gB, 1, 0, 0, BOFF);
  STAGE(gA, 0, 1, 1, 0);    STAGE(gA, 1, 1, 1, 0);
  asm volatile("s_waitcnt vmcnt(4)" ::: "memory");   // tile0 landed; A(1) in flight
  __builtin_amdgcn_s_barrier();
  rdB(0, 0, bA);                                     // b01 of tile 0

  for (int T = 0; T < NT; ++T) {
    const int cur = T & 1, nxt = cur ^ 1;
    const int tp1 = (T + 1 < NT) ? T + 1 : NT - 1;
    const int tp2 = (T + 2 < NT) ? T + 2 : NT - 1;

    // P1: (m0-3, n0-1)  [8 ds_reads]
    rdA(cur, a0, 0);
    STAGE(gB, 0, tp1, nxt, BOFF);
    __builtin_amdgcn_s_barrier();
    asm volatile("s_waitcnt lgkmcnt(0)" ::: "memory");
    __builtin_amdgcn_s_setprio(1);
    MFMA16(0, 0, a0, bA);
    __builtin_amdgcn_s_setprio(0);
    __builtin_amdgcn_s_barrier();

    // P2: (m4-7, n0-1)  [8 ds_reads]
    rdA(cur, a1, 4);
    STAGE(gB, 1, tp1, nxt, BOFF);
    __builtin_amdgcn_s_barrier();
    asm volatile("s_waitcnt lgkmcnt(0)" ::: "memory");
    __builtin_amdgcn_s_setprio(1);
    MFMA16(4, 0, a1, bA);
    __builtin_amdgcn_s_setprio(0);
    __builtin_amdgcn_s_barrier();

    // P3: (m4-7, n2-3)  [4 ds_reads]
    rdB(cur, 2, bB);
    STAGE(gA, 0, tp2, cur, 0);           // cur A half0: last read completed end-P2
    __builtin_amdgcn_s_barrier();
    asm volatile("s_waitcnt lgkmcnt(0)" ::: "memory");
    __builtin_amdgcn_s_setprio(1);
    MFMA16(4, 2, a1, bB);
    __builtin_amdgcn_s_setprio(0);
    __builtin_amdgcn_s_barrier();

    // P4: (m0-3, n2-3)  [4 ds_reads: next tile's b01, after vmcnt+barrier]
    STAGE(gA, 1, tp2, cur, 0);
    asm volatile("s_waitcnt vmcnt(4)" ::: "memory"); // tile T+1 (A+B) fully landed
    __builtin_amdgcn_s_barrier();
    rdB(nxt, 0, bA);                     // b01 of tile T+1 (overlaps MFMA below)
    __builtin_amdgcn_s_setprio(1);
    MFMA16(0, 2, a0, bB);
    __builtin_amdgcn_s_setprio(0);
    __builtin_amdgcn_s_barrier();
  }

  if constexpr (SOFTMAX) {
    // logits = acc/4; softmax over the wave's 64-col block (= one head block)
    unsigned short* attn = reinterpret_cast<unsigned short*>(Cout);
    constexpr float CEXP = 0.25f * 1.44269504088896340736f; // log2(e)/4
    #pragma unroll
    for (int m = 0; m < 8; ++m) {
      const int row = brow + wm * 128 + m * 16 + fq * 4;
      #pragma unroll
      for (int j = 0; j < 4; ++j) {
        float v0 = acc[m][0][j], v1 = acc[m][1][j];
        float v2 = acc[m][2][j], v3 = acc[m][3][j];
        float mx = fmaxf(fmaxf(v0, v1), fmaxf(v2, v3));
        #pragma unroll
        for (int s = 1; s < 16; s <<= 1) mx = fmaxf(mx, __shfl_xor(mx, s, 64));
        float p0 = exp2f((v0 - mx) * CEXP);
        float p1 = exp2f((v1 - mx) * CEXP);
        float p2 = exp2f((v2 - mx) * CEXP);
        float p3 = exp2f((v3 - mx) * CEXP);
        float sm = p0 + p1 + p2 + p3;
        #pragma unroll
        for (int s = 1; s < 16; s <<= 1) sm += __shfl_xor(sm, s, 64);
        const float inv = 1.0f / sm;
        unsigned short* dst =
            attn + (size_t)(row + j) * ND + (bcol + wn * 64 + fr);
        dst[0]  = f2bf_rne(p0 * inv);
        dst[16] = f2bf_rne(p1 * inv);
        dst[32] = f2bf_rne(p2 * inv);
        dst[48] = f2bf_rne(p3 * inv);
      }
    }
  } else {
    float* Cf = reinterpret_cast<float*>(Cout);
    #pragma unroll
    for (int m = 0; m < 8; ++m) {
      const int row = brow + wm * 128 + m * 16 + fq * 4;
      #pragma unroll
      for (int n = 0; n < 4; ++n) {
        const int col = bcol + wn * 64 + n * 16 + fr;
        #pragma unroll
        for (int j = 0; j < 4; ++j)
          Cf[(size_t)(row + j) * ND + col] = acc[m][n][j];
      }
    }
  }
}

extern "C" void kernel_launch(void* const* d_in, const int* in_sizes, int n_in,
                              void* d_out, int out_size, void* d_ws, size_t ws_size,
                              hipStream_t stream) {
  const float* x  = (const float*)d_in[0];   // [4,8192,1024] f32
  const float* W1 = (const float*)d_in[1];   // [3072,1024]  f32 (rows 0..1023 = Wq)
  const float* W2 = (const float*)d_in[2];   // [1024,1024]  f32
  float* out = (float*)d_out;

  char* ws = (char*)d_ws;
  unsigned short* xb   = (unsigned short*)(ws);
  unsigned short* w1b  = (unsigned short*)(ws + (size_t)67108864);
  unsigned short* w2b  = (unsigned short*)(ws + (size_t)69206016);
  unsigned short* attn = (unsigned short*)(ws + (size_t)71303168);

  hipFuncSetAttribute(reinterpret_cast<const void*>(gemm8<1>),
                      hipFuncAttributeMaxDynamicSharedMemorySize, 131072);
  hipFuncSetAttribute(reinterpret_cast<const void*>(gemm8<0>),
                      hipFuncAttributeMaxDynamicSharedMemorySize, 131072);

  cast_f32_to_bf16<<<2048, 256, 0, stream>>>(x,  xb,  MTOT * KD / 4);
  cast_f32_to_bf16<<<512,  256, 0, stream>>>(W1, w1b, KD * KD / 4);
  cast_f32_to_bf16<<<512,  256, 0, stream>>>(W2, w2b, KD * KD / 4);

  const int nblk = (MTOT / BM) * (ND / BN);   // 128 * 4 = 512
  gemm8<1><<<nblk, 512, 131072, stream>>>(xb, w1b, (void*)attn);
  gemm8<0><<<nblk, 512, 131072, stream>>>(attn, w2b, (void*)out);
}